// Round 9
// baseline (186.093 us; speedup 1.0000x reference)
//
#include <hip/hip_runtime.h>

// x (4096, 2, 1024) fp32.  P_i = x[i,0,:], A_j = x[i,1,:]
// out[0] = 1.0 exactly; out[1] = prec1 = 100*mean(argmax_j sim[i,j] == i)
// argmax_j sim[i,j] == argmax_j dot(P_i,A_j)*inv_norm(A_j).
// R9: 2-pass bf16-split (Phi*Ahi + Phi*Alo), NO LDS / NO BARRIERS.
// Prep writes P/A in MFMA-fragment order: frag(blk32, kh16) = 1KB of
// lane*16B, lane=(lh*32+l31) -> (row/col=l31, k=lh*8..+8)  [R4-verified map].
// GEMM waves load fragments straight to VGPRs (coalesced dwordx4) and MFMA;
// compiler pipelines loads with vmcnt(N)-before-use. 256x128 block tile,
// grid 512 (2 blocks/CU), 4 waves of 128x64 (acc=128 AGPR, 2 waves/SIMD).

#define NROWS 4096
#define DDIM  1024
#define XSTR  2048

typedef unsigned int u32;
typedef unsigned long long u64;
typedef __attribute__((ext_vector_type(8))) short bf16x8;
typedef __attribute__((ext_vector_type(16))) float f32x16;

__device__ __forceinline__ unsigned int fkey(float f) {
    unsigned int u = __float_as_uint(f);
    return (u & 0x80000000u) ? ~u : (u | 0x80000000u);
}

__device__ __forceinline__ u64 shfl_xor_u64(u64 v, int m) {
    unsigned int lo = (unsigned int)v;
    unsigned int hi = (unsigned int)(v >> 32);
    lo = __shfl_xor(lo, m, 64);
    hi = __shfl_xor(hi, m, 64);
    return ((u64)hi << 32) | lo;
}

__device__ __forceinline__ unsigned short f2bf(float f) {
    unsigned u = __float_as_uint(f);
    return (unsigned short)((u + 0x7FFFu + ((u >> 16) & 1u)) >> 16);
}

__device__ __forceinline__ void split4(float4 v, ushort4* h, ushort4* l) {
    float f[4] = {v.x, v.y, v.z, v.w};
    unsigned short hh[4], ll[4];
#pragma unroll
    for (int q = 0; q < 4; ++q) {
        hh[q] = f2bf(f[q]);
        float hf = __uint_as_float(((unsigned)hh[q]) << 16);
        ll[q] = f2bf(f[q] - hf);
    }
    *h = make_ushort4(hh[0], hh[1], hh[2], hh[3]);
    *l = make_ushort4(ll[0], ll[1], ll[2], ll[3]);
}

// Workspace layout (bytes): fragment-ordered arrays, 8 MB each.
#define PF_OFF  0u
#define AHF_OFF 8388608u
#define ALF_OFF 16777216u
#define INV_OFF 25165824u
#define PCK_OFF 25182208u
#define WS_NEED 25214976u

// Prep: one block per row. Writes Phi / Ahi / Alo in fragment order:
// element (r,k) -> ushort idx ((r>>5)*64 + (k>>4))*512 + ((k>>3)&1)*256
//                   + (r&31)*8 + (k&7).
// Thread t handles k=[4t,4t+4) (same lh, same j-run -> one ushort4 store).
__global__ __launch_bounds__(256) void prep_kernel(const float* __restrict__ x,
                                                   unsigned short* __restrict__ Pf,
                                                   unsigned short* __restrict__ Ahf,
                                                   unsigned short* __restrict__ Alf,
                                                   float* __restrict__ inv_an,
                                                   u64* __restrict__ packed) {
    __shared__ float red[4];
    const int b = blockIdx.x;
    const int t = threadIdx.x;

    float4 pv = *(const float4*)(x + (size_t)b * XSTR + t * 4);
    float4 av = *(const float4*)(x + (size_t)b * XSTR + DDIM + t * 4);

    const int sidx = ((b >> 5) * 64 + (t >> 2)) * 512 + ((t >> 1) & 1) * 256
                     + (b & 31) * 8 + 4 * (t & 1);

    ushort4 ph = make_ushort4(f2bf(pv.x), f2bf(pv.y), f2bf(pv.z), f2bf(pv.w));
    *(ushort4*)(Pf + sidx) = ph;

    ushort4 h, l;
    split4(av, &h, &l);
    *(ushort4*)(Ahf + sidx) = h;
    *(ushort4*)(Alf + sidx) = l;

    float s = av.x * av.x + av.y * av.y + av.z * av.z + av.w * av.w;
#pragma unroll
    for (int off = 32; off > 0; off >>= 1) s += __shfl_down(s, off, 64);
    if ((t & 63) == 0) red[t >> 6] = s;
    __syncthreads();
    if (t == 0) {
        inv_an[b] = 1.0f / sqrtf(red[0] + red[1] + red[2] + red[3]);
        packed[b] = 0ULL;
    }
}

// Fragment load: frag (blk32, kh16) lives at byte ((blk*64 + kh)*1024 + lane*16).
#define FRAG(base, blk, kh) (*(const bf16x8*)((base) + (((size_t)(blk) * 64 + (kh)) << 10)))

// MFMA GEMM + argmax, LDS-free. 256x128 block tile, 4 waves (2x2) of 128x64.
// Per 16-k step each wave loads 4 P-frags + 2 Ahi + 2 Alo (8 dwordx4) and
// issues 16 MFMAs; software-pipelined one step ahead (ping-pong frag regs).
// XCD swizzle: bid&7 = XCD, each XCD owns a 4(r) x 16(c) region of 16x32.
__global__ __launch_bounds__(256, 2) void mfma_gemm_argmax(const unsigned short* __restrict__ Pf,
                                                           const unsigned short* __restrict__ Ahf,
                                                           const unsigned short* __restrict__ Alf,
                                                           const float* __restrict__ inv_an,
                                                           u64* __restrict__ packed) {
    const int bid = blockIdx.x;
    const int xcd = bid & 7;
    const int s = bid >> 3;                        // 0..63
    const int rblk = (xcd >> 1) * 4 + (s >> 4);    // 0..15  (256-row tiles)
    const int cblk = (xcd & 1) * 16 + (s & 15);    // 0..31  (128-col tiles)
    const int r0 = rblk * 256;
    const int c0 = cblk * 128;

    const int wave = threadIdx.x >> 6;
    const int lane = threadIdx.x & 63;
    const int l31 = lane & 31;
    const int lh = lane >> 5;
    const int wm = wave & 1;   // rows wm*128..+127
    const int wn = wave >> 1;  // cols wn*64..+63

    const int mb0 = rblk * 8 + wm * 4;  // first 32-row block index
    const int nb0 = cblk * 4 + wn * 2;  // first 32-col block index

    const char* pP = (const char*)Pf + (size_t)lane * 16 + ((size_t)mb0 << 16);
    const char* pH = (const char*)Ahf + (size_t)lane * 16 + ((size_t)nb0 << 16);
    const char* pL = (const char*)Alf + (size_t)lane * 16 + ((size_t)nb0 << 16);

    f32x16 zero16 = {0.f,0.f,0.f,0.f,0.f,0.f,0.f,0.f,0.f,0.f,0.f,0.f,0.f,0.f,0.f,0.f};
    f32x16 acc[4][2];
#pragma unroll
    for (int i = 0; i < 4; ++i)
#pragma unroll
        for (int j = 0; j < 2; ++j) acc[i][j] = zero16;

    bf16x8 phA[4], ahA[2], alA[2], phB[4], ahB[2], alB[2];

    // preload kh=0 into A
#pragma unroll
    for (int mt = 0; mt < 4; ++mt) phA[mt] = FRAG(pP, mt, 0);
#pragma unroll
    for (int nt = 0; nt < 2; ++nt) { ahA[nt] = FRAG(pH, nt, 0); alA[nt] = FRAG(pL, nt, 0); }

    for (int kh = 0; kh < 64; kh += 2) {
        // load kh+1 into B
#pragma unroll
        for (int mt = 0; mt < 4; ++mt) phB[mt] = FRAG(pP, mt, kh + 1);
#pragma unroll
        for (int nt = 0; nt < 2; ++nt) { ahB[nt] = FRAG(pH, nt, kh + 1); alB[nt] = FRAG(pL, nt, kh + 1); }

        // compute kh with A
#pragma unroll
        for (int mt = 0; mt < 4; ++mt)
#pragma unroll
            for (int nt = 0; nt < 2; ++nt)
                acc[mt][nt] = __builtin_amdgcn_mfma_f32_32x32x16_bf16(phA[mt], ahA[nt], acc[mt][nt], 0, 0, 0);
#pragma unroll
        for (int mt = 0; mt < 4; ++mt)
#pragma unroll
            for (int nt = 0; nt < 2; ++nt)
                acc[mt][nt] = __builtin_amdgcn_mfma_f32_32x32x16_bf16(phA[mt], alA[nt], acc[mt][nt], 0, 0, 0);

        // load kh+2 into A
        if (kh + 2 < 64) {
#pragma unroll
            for (int mt = 0; mt < 4; ++mt) phA[mt] = FRAG(pP, mt, kh + 2);
#pragma unroll
            for (int nt = 0; nt < 2; ++nt) { ahA[nt] = FRAG(pH, nt, kh + 2); alA[nt] = FRAG(pL, nt, kh + 2); }
        }

        // compute kh+1 with B
#pragma unroll
        for (int mt = 0; mt < 4; ++mt)
#pragma unroll
            for (int nt = 0; nt < 2; ++nt)
                acc[mt][nt] = __builtin_amdgcn_mfma_f32_32x32x16_bf16(phB[mt], ahB[nt], acc[mt][nt], 0, 0, 0);
#pragma unroll
        for (int mt = 0; mt < 4; ++mt)
#pragma unroll
            for (int nt = 0; nt < 2; ++nt)
                acc[mt][nt] = __builtin_amdgcn_mfma_f32_32x32x16_bf16(phB[mt], alB[nt], acc[mt][nt], 0, 0, 0);
    }

    // ---- epilogue ----
    float ian[2];
#pragma unroll
    for (int nt = 0; nt < 2; ++nt) ian[nt] = inv_an[c0 + wn * 64 + nt * 32 + l31];

    // 32x32 C/D layout (m74/m101): col = lane&31, row = (reg&3)+8*(reg>>2)+4*(lane>>5)
#pragma unroll
    for (int mt = 0; mt < 4; ++mt)
#pragma unroll
        for (int reg = 0; reg < 16; ++reg) {
            const int row = r0 + wm * 128 + mt * 32 + (reg & 3) + 8 * (reg >> 2) + 4 * lh;
            u64 best = 0ULL;
#pragma unroll
            for (int nt = 0; nt < 2; ++nt) {
                const int col = c0 + wn * 64 + nt * 32 + l31;
                const float v = acc[mt][nt][reg] * ian[nt];
                const u64 p = ((u64)fkey(v) << 32) | (unsigned int)(~col);
                best = best > p ? best : p;
            }
#pragma unroll
            for (int m = 1; m <= 16; m <<= 1) {
                const u64 o = shfl_xor_u64(best, m);
                best = best > o ? best : o;
            }
            if (l31 == 0) atomicMax(&packed[row], best);
        }
}

// ---------------- fallback fp32 path (proven R1) ----------------
__global__ __launch_bounds__(256) void norms_kernel(const float* __restrict__ x,
                                                    float* __restrict__ inv_an,
                                                    u64* __restrict__ packed) {
    int gid  = blockIdx.x * 256 + threadIdx.x;
    int j    = gid >> 6;
    int lane = threadIdx.x & 63;
    if (gid < NROWS) packed[gid] = 0ULL;
    const float4* a = (const float4*)(x + (size_t)j * XSTR + DDIM);
    float s = 0.0f;
#pragma unroll
    for (int i = 0; i < 4; ++i) {
        float4 v = a[lane + i * 64];
        s += v.x * v.x + v.y * v.y + v.z * v.z + v.w * v.w;
    }
#pragma unroll
    for (int off = 32; off > 0; off >>= 1) s += __shfl_down(s, off, 64);
    if (lane == 0) inv_an[j] = 1.0f / sqrtf(s);
}

__global__ __launch_bounds__(256) void gemm_argmax_kernel(const float* __restrict__ x,
                                                          const float* __restrict__ inv_an,
                                                          u64* __restrict__ packed) {
    __shared__ __align__(16) float Pt[16][128];
    __shared__ __align__(16) float At[16][128];
    const int r0 = blockIdx.x * 128;
    const int c0 = blockIdx.y * 128;
    const int t = threadIdx.x;
    const int tx = t & 15;
    const int ty = t >> 4;
    const int srow = t >> 1;
    const int skq = (t & 1) * 8;
    float acc[8][8];
#pragma unroll
    for (int r = 0; r < 8; ++r)
#pragma unroll
        for (int c = 0; c < 8; ++c) acc[r][c] = 0.0f;
    const float* gp = x + (size_t)(r0 + srow) * XSTR + skq;
    const float* ga = x + (size_t)(c0 + srow) * XSTR + DDIM + skq;
    for (int k0 = 0; k0 < DDIM; k0 += 16) {
        __syncthreads();
        float4 p0 = *(const float4*)(gp + k0);
        float4 p1 = *(const float4*)(gp + k0 + 4);
        float4 a0 = *(const float4*)(ga + k0);
        float4 a1 = *(const float4*)(ga + k0 + 4);
        Pt[skq + 0][srow] = p0.x; Pt[skq + 1][srow] = p0.y;
        Pt[skq + 2][srow] = p0.z; Pt[skq + 3][srow] = p0.w;
        Pt[skq + 4][srow] = p1.x; Pt[skq + 5][srow] = p1.y;
        Pt[skq + 6][srow] = p1.z; Pt[skq + 7][srow] = p1.w;
        At[skq + 0][srow] = a0.x; At[skq + 1][srow] = a0.y;
        At[skq + 2][srow] = a0.z; At[skq + 3][srow] = a0.w;
        At[skq + 4][srow] = a1.x; At[skq + 5][srow] = a1.y;
        At[skq + 6][srow] = a1.z; At[skq + 7][srow] = a1.w;
        __syncthreads();
#pragma unroll
        for (int kk = 0; kk < 16; ++kk) {
            float pr[8], ar[8];
            *(float4*)&pr[0] = *(const float4*)&Pt[kk][ty * 8];
            *(float4*)&pr[4] = *(const float4*)&Pt[kk][ty * 8 + 4];
            *(float4*)&ar[0] = *(const float4*)&At[kk][tx * 8];
            *(float4*)&ar[4] = *(const float4*)&At[kk][tx * 8 + 4];
#pragma unroll
            for (int r = 0; r < 8; ++r)
#pragma unroll
                for (int c = 0; c < 8; ++c) acc[r][c] += pr[r] * ar[c];
        }
    }
    float ian[8];
#pragma unroll
    for (int c = 0; c < 8; ++c) ian[c] = inv_an[c0 + tx * 8 + c];
#pragma unroll
    for (int r = 0; r < 8; ++r) {
        int row = r0 + ty * 8 + r;
        u64 best = 0ULL;
#pragma unroll
        for (int c = 0; c < 8; ++c) {
            int col = c0 + tx * 8 + c;
            float v = acc[r][c] * ian[c];
            u64 p = ((u64)fkey(v) << 32) | (unsigned int)(~col);
            best = best > p ? best : p;
        }
#pragma unroll
        for (int m = 1; m <= 8; m <<= 1) {
            u64 o = shfl_xor_u64(best, m);
            best = best > o ? best : o;
        }
        if (tx == 0) atomicMax(&packed[row], best);
    }
}

// ---------------- finalize ----------------
__global__ __launch_bounds__(256) void finalize_kernel(const u64* __restrict__ packed,
                                                       float* __restrict__ out) {
    __shared__ int cnt_s;
    int t = threadIdx.x;
    if (t == 0) cnt_s = 0;
    __syncthreads();
    int c = 0;
    for (int r = t; r < NROWS; r += 256) {
        unsigned int col = ~(unsigned int)(packed[r] & 0xFFFFFFFFULL);
        c += (col == (unsigned int)r) ? 1 : 0;
    }
#pragma unroll
    for (int off = 32; off > 0; off >>= 1) c += __shfl_down(c, off, 64);
    if ((t & 63) == 0) atomicAdd(&cnt_s, c);
    __syncthreads();
    if (t == 0) {
        out[0] = 1.0f;
        out[1] = 100.0f * (float)cnt_s / (float)NROWS;
    }
}

extern "C" void kernel_launch(void* const* d_in, const int* in_sizes, int n_in,
                              void* d_out, int out_size, void* d_ws, size_t ws_size,
                              hipStream_t stream) {
    (void)in_sizes; (void)n_in; (void)out_size;
    const float* x = (const float*)d_in[0];
    float* out = (float*)d_out;

    if (ws_size >= (size_t)WS_NEED) {
        char* ws = (char*)d_ws;
        unsigned short* Pf = (unsigned short*)(ws + PF_OFF);
        unsigned short* Ahf = (unsigned short*)(ws + AHF_OFF);
        unsigned short* Alf = (unsigned short*)(ws + ALF_OFF);
        float* inv_an = (float*)(ws + INV_OFF);
        u64* packed = (u64*)(ws + PCK_OFF);

        prep_kernel<<<NROWS, 256, 0, stream>>>(x, Pf, Ahf, Alf, inv_an, packed);
        mfma_gemm_argmax<<<512, 256, 0, stream>>>(Pf, Ahf, Alf, inv_an, packed);
        finalize_kernel<<<1, 256, 0, stream>>>(packed, out);
    } else {
        float* inv_an = (float*)d_ws;
        u64* packed = (u64*)((char*)d_ws + NROWS * sizeof(float));
        norms_kernel<<<NROWS / 4, 256, 0, stream>>>(x, inv_an, packed);
        dim3 grid(NROWS / 128, NROWS / 128);
        gemm_argmax_kernel<<<grid, 256, 0, stream>>>(x, inv_an, packed);
        finalize_kernel<<<1, 256, 0, stream>>>(packed, out);
    }
}

// Round 10
// 157.835 us; speedup vs baseline: 1.1790x; 1.1790x over previous
//
#include <hip/hip_runtime.h>

// x (4096, 2, 1024) fp32.  P_i = x[i,0,:], A_j = x[i,1,:]
// out[0] = 1.0 exactly; out[1] = prec1 = 100*mean(argmax_j sim[i,j] == i)
// argmax_j sim[i,j] == argmax_j dot(P_i,A_j)*inv_norm(A_j).
// R10: 1-pass bf16 MFMA (dot ~= bf16(P)*bf16(A), err sigma ~5e-5 sim vs
// diag-critical margins ~8e-3). R7's verified structure: 256x256 tile,
// 4 waves of 128x128, 32x32x16 MFMA, BK=32, double-buffered 2x32KB LDS,
// XCD-swizzled grid 256. Finalize fused into the GEMM (last-block counter).

#define NROWS 4096
#define DDIM  1024
#define XSTR  2048

typedef unsigned int u32;
typedef unsigned long long u64;
typedef __attribute__((ext_vector_type(8))) short bf16x8;
typedef __attribute__((ext_vector_type(16))) float f32x16;

#define GLOBAL_AS __attribute__((address_space(1)))
#define LDS_AS    __attribute__((address_space(3)))

__device__ __forceinline__ void async_load16(const void* g, void* l) {
    __builtin_amdgcn_global_load_lds((GLOBAL_AS const u32*)g, (LDS_AS u32*)l, 16, 0, 0);
}

__device__ __forceinline__ unsigned int fkey(float f) {
    unsigned int u = __float_as_uint(f);
    return (u & 0x80000000u) ? ~u : (u | 0x80000000u);
}

__device__ __forceinline__ u64 shfl_xor_u64(u64 v, int m) {
    unsigned int lo = (unsigned int)v;
    unsigned int hi = (unsigned int)(v >> 32);
    lo = __shfl_xor(lo, m, 64);
    hi = __shfl_xor(hi, m, 64);
    return ((u64)hi << 32) | lo;
}

__device__ __forceinline__ unsigned short f2bf(float f) {
    unsigned u = __float_as_uint(f);
    return (unsigned short)((u + 0x7FFFu + ((u >> 16) & 1u)) >> 16);
}

// Workspace layout (bytes):
#define PHI_OFF  0u
#define ABF_OFF  8388608u
#define INV_OFF  16777216u
#define PCK_OFF  16793600u
#define DONE_OFF 16826368u
#define WS_NEED  16826432u

// Prep: one block per row, fully coalesced. Phi = bf16(P), Abf = bf16(A),
// row-major; block-reduce anchor norm (fp32); zero packed[row] and done.
__global__ __launch_bounds__(256) void prep_kernel(const float* __restrict__ x,
                                                   unsigned short* __restrict__ Phi,
                                                   unsigned short* __restrict__ Abf,
                                                   float* __restrict__ inv_an,
                                                   u64* __restrict__ packed,
                                                   unsigned int* __restrict__ done) {
    __shared__ float red[4];
    const int b = blockIdx.x;
    const int t = threadIdx.x;

    float4 pv = *(const float4*)(x + (size_t)b * XSTR + t * 4);
    float4 av = *(const float4*)(x + (size_t)b * XSTR + DDIM + t * 4);

    ((ushort4*)Phi)[(size_t)b * 256 + t] =
        make_ushort4(f2bf(pv.x), f2bf(pv.y), f2bf(pv.z), f2bf(pv.w));
    ((ushort4*)Abf)[(size_t)b * 256 + t] =
        make_ushort4(f2bf(av.x), f2bf(av.y), f2bf(av.z), f2bf(av.w));

    float s = av.x * av.x + av.y * av.y + av.z * av.z + av.w * av.w;
#pragma unroll
    for (int off = 32; off > 0; off >>= 1) s += __shfl_down(s, off, 64);
    if ((t & 63) == 0) red[t >> 6] = s;
    __syncthreads();
    if (t == 0) {
        inv_an[b] = 1.0f / sqrtf(red[0] + red[1] + red[2] + red[3]);
        packed[b] = 0ULL;
        if (b == 0) *done = 0u;
    }
}

// MFMA GEMM + argmax + fused finalize. 256x256 block tile, 4 waves (2x2)
// of 128x128. BK=32: 32 segs x 1KB per buffer (seg = 32 rows x 16 k at byte
// q*512+r*16, the order global_load_lds produces). Buffer layout (ushort):
// arr(0=Phi,1=Abf)*8192 + (rb*2+kh)*512. Wave w stages segs [w*8, w*8+8).
// XCD swizzle: bid&7 = XCD, each XCD owns a 4(r) x 8(c) region of 16x16.
// Last block (device-scope done counter) counts argmax==row and writes out.
__global__ __launch_bounds__(256, 1) void mfma_gemm_argmax(const unsigned short* __restrict__ Phi,
                                                           const unsigned short* __restrict__ Abf,
                                                           const float* __restrict__ inv_an,
                                                           u64* __restrict__ packed,
                                                           unsigned int* __restrict__ done,
                                                           float* __restrict__ out) {
    __shared__ __align__(16) unsigned short lds[32768];  // 2 bufs x 16384 ushort (32KB each)
    __shared__ unsigned int lastflag;
    __shared__ int cnt[4];

    const int bid = blockIdx.x;
    const int xcd = bid & 7;
    const int slt = bid >> 3;                       // 0..31
    const int rblk = (xcd >> 1) * 4 + (slt >> 3);   // 0..15
    const int cblk = (xcd & 1) * 8 + (slt & 7);     // 0..15
    const int r0 = rblk * 256;
    const int c0 = cblk * 256;

    const int wave = threadIdx.x >> 6;
    const int lane = threadIdx.x & 63;
    const int l31 = lane & 31;
    const int lh = lane >> 5;
    const int wm = wave & 1;   // m-half: rows wm*128..+127
    const int wn = wave >> 1;  // n-half: cols wn*128..+127

    // ---- staging: 32 segs (arr*16 + rb*2 + kh), wave w stages [w*8, w*8+8) ----
    const unsigned short* srcs[2] = {Phi, Abf};
    const char* gp[8];
    int ldst[8];  // LDS ushort offset within a buffer
#pragma unroll
    for (int j = 0; j < 8; ++j) {
        const int g = wave * 8 + j;
        const int arr = g >> 4;
        const int rb = (g & 15) >> 1;
        const int kh = g & 1;
        const int baserow = (arr == 0) ? r0 : c0;
        gp[j] = (const char*)(srcs[arr] + (size_t)(baserow + rb * 32 + l31) * DDIM + kh * 16) + lh * 16;
        ldst[j] = g * 512;
    }

    // frag read offset within a 1KB seg (ushort units): byte lh*512+l31*16
    const int lof = lh * 256 + l31 * 8;

    f32x16 zero16 = {0.f,0.f,0.f,0.f,0.f,0.f,0.f,0.f,0.f,0.f,0.f,0.f,0.f,0.f,0.f,0.f};
    f32x16 acc[4][4];
#pragma unroll
    for (int i = 0; i < 4; ++i)
#pragma unroll
        for (int j = 0; j < 4; ++j) acc[i][j] = zero16;

    // prologue: stage chunk 0 -> buf 0
#pragma unroll
    for (int j = 0; j < 8; ++j) async_load16(gp[j], lds + ldst[j]);

    for (int kc = 0; kc < 32; ++kc) {
        __syncthreads();  // vmcnt drained: chunk kc visible in buf kc&1
        const int cur = (kc & 1) * 16384;
        if (kc < 31) {
            const int nxt = ((kc + 1) & 1) * 16384;
            const int gofs = (kc + 1) * 64;  // bytes: 32 k * 2B
#pragma unroll
            for (int j = 0; j < 8; ++j)
                async_load16(gp[j] + gofs, lds + nxt + ldst[j]);
        }

#pragma unroll
        for (int kh = 0; kh < 2; ++kh) {
            bf16x8 ph[4], ab[4];
#pragma unroll
            for (int t = 0; t < 4; ++t) {
                const int prb = wm * 4 + t;
                const int arb = wn * 4 + t;
                ph[t] = *(const bf16x8*)(lds + cur + (prb * 2 + kh) * 512 + lof);
                ab[t] = *(const bf16x8*)(lds + cur + 8192 + (arb * 2 + kh) * 512 + lof);
            }
#pragma unroll
            for (int mt = 0; mt < 4; ++mt)
#pragma unroll
                for (int nt = 0; nt < 4; ++nt)
                    acc[mt][nt] = __builtin_amdgcn_mfma_f32_32x32x16_bf16(ph[mt], ab[nt], acc[mt][nt], 0, 0, 0);
        }
    }

    // ---- epilogue ----
    float ian[4];
#pragma unroll
    for (int nt = 0; nt < 4; ++nt) ian[nt] = inv_an[c0 + wn * 128 + nt * 32 + l31];

    // 32x32 C/D layout (m74/m101): col = lane&31, row = (reg&3)+8*(reg>>2)+4*(lane>>5)
#pragma unroll
    for (int mt = 0; mt < 4; ++mt)
#pragma unroll
        for (int reg = 0; reg < 16; ++reg) {
            const int row = r0 + wm * 128 + mt * 32 + (reg & 3) + 8 * (reg >> 2) + 4 * lh;
            u64 best = 0ULL;
#pragma unroll
            for (int nt = 0; nt < 4; ++nt) {
                const int col = c0 + wn * 128 + nt * 32 + l31;
                const float v = acc[mt][nt][reg] * ian[nt];
                const u64 p = ((u64)fkey(v) << 32) | (unsigned int)(~col);
                best = best > p ? best : p;
            }
#pragma unroll
            for (int m = 1; m <= 16; m <<= 1) {
                const u64 o = shfl_xor_u64(best, m);
                best = best > o ? best : o;
            }
            if (l31 == 0) atomicMax(&packed[row], best);
        }

    // ---- fused finalize: last block counts and writes out ----
    __syncthreads();
    if (threadIdx.x == 0) {
        __threadfence();  // publish this block's atomicMax results
        unsigned int old = atomicAdd(done, 1u);
        lastflag = (old == 255u) ? 1u : 0u;
    }
    __syncthreads();
    if (lastflag) {
        int c = 0;
        for (int r = threadIdx.x; r < NROWS; r += 256) {
            // RMW-as-load: device-coherent read of other blocks' atomicMax
            u64 v = atomicAdd(&packed[r], 0ULL);
            unsigned int col = ~(unsigned int)(v & 0xFFFFFFFFULL);
            c += (col == (unsigned int)r) ? 1 : 0;
        }
#pragma unroll
        for (int off = 32; off > 0; off >>= 1) c += __shfl_down(c, off, 64);
        if ((threadIdx.x & 63) == 0) cnt[threadIdx.x >> 6] = c;
        __syncthreads();
        if (threadIdx.x == 0) {
            out[0] = 1.0f;  // exp(temploss - stop_gradient(temploss)) == 1 exactly
            out[1] = 100.0f * (float)(cnt[0] + cnt[1] + cnt[2] + cnt[3]) / (float)NROWS;
        }
    }
}

// ---------------- fallback fp32 path (proven R1) ----------------
__global__ __launch_bounds__(256) void norms_kernel(const float* __restrict__ x,
                                                    float* __restrict__ inv_an,
                                                    u64* __restrict__ packed) {
    int gid  = blockIdx.x * 256 + threadIdx.x;
    int j    = gid >> 6;
    int lane = threadIdx.x & 63;
    if (gid < NROWS) packed[gid] = 0ULL;
    const float4* a = (const float4*)(x + (size_t)j * XSTR + DDIM);
    float s = 0.0f;
#pragma unroll
    for (int i = 0; i < 4; ++i) {
        float4 v = a[lane + i * 64];
        s += v.x * v.x + v.y * v.y + v.z * v.z + v.w * v.w;
    }
#pragma unroll
    for (int off = 32; off > 0; off >>= 1) s += __shfl_down(s, off, 64);
    if (lane == 0) inv_an[j] = 1.0f / sqrtf(s);
}

__global__ __launch_bounds__(256) void gemm_argmax_kernel(const float* __restrict__ x,
                                                          const float* __restrict__ inv_an,
                                                          u64* __restrict__ packed) {
    __shared__ __align__(16) float Pt[16][128];
    __shared__ __align__(16) float At[16][128];
    const int r0 = blockIdx.x * 128;
    const int c0 = blockIdx.y * 128;
    const int t = threadIdx.x;
    const int tx = t & 15;
    const int ty = t >> 4;
    const int srow = t >> 1;
    const int skq = (t & 1) * 8;
    float acc[8][8];
#pragma unroll
    for (int r = 0; r < 8; ++r)
#pragma unroll
        for (int c = 0; c < 8; ++c) acc[r][c] = 0.0f;
    const float* gp = x + (size_t)(r0 + srow) * XSTR + skq;
    const float* ga = x + (size_t)(c0 + srow) * XSTR + DDIM + skq;
    for (int k0 = 0; k0 < DDIM; k0 += 16) {
        __syncthreads();
        float4 p0 = *(const float4*)(gp + k0);
        float4 p1 = *(const float4*)(gp + k0 + 4);
        float4 a0 = *(const float4*)(ga + k0);
        float4 a1 = *(const float4*)(ga + k0 + 4);
        Pt[skq + 0][srow] = p0.x; Pt[skq + 1][srow] = p0.y;
        Pt[skq + 2][srow] = p0.z; Pt[skq + 3][srow] = p0.w;
        Pt[skq + 4][srow] = p1.x; Pt[skq + 5][srow] = p1.y;
        Pt[skq + 6][srow] = p1.z; Pt[skq + 7][srow] = p1.w;
        At[skq + 0][srow] = a0.x; At[skq + 1][srow] = a0.y;
        At[skq + 2][srow] = a0.z; At[skq + 3][srow] = a0.w;
        At[skq + 4][srow] = a1.x; At[skq + 5][srow] = a1.y;
        At[skq + 6][srow] = a1.z; At[skq + 7][srow] = a1.w;
        __syncthreads();
#pragma unroll
        for (int kk = 0; kk < 16; ++kk) {
            float pr[8], ar[8];
            *(float4*)&pr[0] = *(const float4*)&Pt[kk][ty * 8];
            *(float4*)&pr[4] = *(const float4*)&Pt[kk][ty * 8 + 4];
            *(float4*)&ar[0] = *(const float4*)&At[kk][tx * 8];
            *(float4*)&ar[4] = *(const float4*)&At[kk][tx * 8 + 4];
#pragma unroll
            for (int r = 0; r < 8; ++r)
#pragma unroll
                for (int c = 0; c < 8; ++c) acc[r][c] += pr[r] * ar[c];
        }
    }
    float ian[8];
#pragma unroll
    for (int c = 0; c < 8; ++c) ian[c] = inv_an[c0 + tx * 8 + c];
#pragma unroll
    for (int r = 0; r < 8; ++r) {
        int row = r0 + ty * 8 + r;
        u64 best = 0ULL;
#pragma unroll
        for (int c = 0; c < 8; ++c) {
            int col = c0 + tx * 8 + c;
            float v = acc[r][c] * ian[c];
            u64 p = ((u64)fkey(v) << 32) | (unsigned int)(~col);
            best = best > p ? best : p;
        }
#pragma unroll
        for (int m = 1; m <= 8; m <<= 1) {
            u64 o = shfl_xor_u64(best, m);
            best = best > o ? best : o;
        }
        if (tx == 0) atomicMax(&packed[row], best);
    }
}

__global__ __launch_bounds__(256) void finalize_kernel(const u64* __restrict__ packed,
                                                       float* __restrict__ out) {
    __shared__ int cnt_s;
    int t = threadIdx.x;
    if (t == 0) cnt_s = 0;
    __syncthreads();
    int c = 0;
    for (int r = t; r < NROWS; r += 256) {
        unsigned int col = ~(unsigned int)(packed[r] & 0xFFFFFFFFULL);
        c += (col == (unsigned int)r) ? 1 : 0;
    }
#pragma unroll
    for (int off = 32; off > 0; off >>= 1) c += __shfl_down(c, off, 64);
    if ((t & 63) == 0) atomicAdd(&cnt_s, c);
    __syncthreads();
    if (t == 0) {
        out[0] = 1.0f;
        out[1] = 100.0f * (float)cnt_s / (float)NROWS;
    }
}

extern "C" void kernel_launch(void* const* d_in, const int* in_sizes, int n_in,
                              void* d_out, int out_size, void* d_ws, size_t ws_size,
                              hipStream_t stream) {
    (void)in_sizes; (void)n_in; (void)out_size;
    const float* x = (const float*)d_in[0];
    float* out = (float*)d_out;

    if (ws_size >= (size_t)WS_NEED) {
        char* ws = (char*)d_ws;
        unsigned short* Phi = (unsigned short*)(ws + PHI_OFF);
        unsigned short* Abf = (unsigned short*)(ws + ABF_OFF);
        float* inv_an = (float*)(ws + INV_OFF);
        u64* packed = (u64*)(ws + PCK_OFF);
        unsigned int* done = (unsigned int*)(ws + DONE_OFF);

        prep_kernel<<<NROWS, 256, 0, stream>>>(x, Phi, Abf, inv_an, packed, done);
        mfma_gemm_argmax<<<256, 256, 0, stream>>>(Phi, Abf, inv_an, packed, done, out);
    } else {
        float* inv_an = (float*)d_ws;
        u64* packed = (u64*)((char*)d_ws + NROWS * sizeof(float));
        norms_kernel<<<NROWS / 4, 256, 0, stream>>>(x, inv_an, packed);
        dim3 grid(NROWS / 128, NROWS / 128);
        gemm_argmax_kernel<<<grid, 256, 0, stream>>>(x, inv_an, packed);
        finalize_kernel<<<1, 256, 0, stream>>>(packed, out);
    }
}

// Round 11
// 131.831 us; speedup vs baseline: 1.4116x; 1.1973x over previous
//
#include <hip/hip_runtime.h>

// x (4096, 2, 1024) fp32.  P_i = x[i,0,:], A_j = x[i,1,:]
// out[0] = 1.0 exactly; out[1] = prec1 = 100*mean(argmax_j sim[i,j] == i)
// argmax_j sim[i,j] == argmax_j dot(P_i,A_j)*inv_norm(A_j).
// R11: 1-pass bf16 MFMA, register-direct (no LDS / no barriers / no DMA).
// Frag-order workspace: 32-row block b's region = 64KB at base + b*65536;
// within region byte = kh*1024 + lane*16, lane=(lh*32+l31) -> (row=l31,
// k=kh*16+lh*8..+8)  [R4/R9-verified A-operand map]. GEMM: 256x256 block
// tile, 4 waves of 128x128, ping-pong frag regs, 16 MFMA per 16-k step.
// Per-CU L2 demand ~31 B/cyc (under ~60 ceiling) -> compute-bound target.
// Fused finalize via device-scope done counter (R10-proven).

#define NROWS 4096
#define DDIM  1024
#define XSTR  2048

typedef unsigned int u32;
typedef unsigned long long u64;
typedef __attribute__((ext_vector_type(8))) short bf16x8;
typedef __attribute__((ext_vector_type(16))) float f32x16;

__device__ __forceinline__ unsigned int fkey(float f) {
    unsigned int u = __float_as_uint(f);
    return (u & 0x80000000u) ? ~u : (u | 0x80000000u);
}

__device__ __forceinline__ u64 shfl_xor_u64(u64 v, int m) {
    unsigned int lo = (unsigned int)v;
    unsigned int hi = (unsigned int)(v >> 32);
    lo = __shfl_xor(lo, m, 64);
    hi = __shfl_xor(hi, m, 64);
    return ((u64)hi << 32) | lo;
}

__device__ __forceinline__ unsigned short f2bf(float f) {
    unsigned u = __float_as_uint(f);
    return (unsigned short)((u + 0x7FFFu + ((u >> 16) & 1u)) >> 16);
}

// Workspace layout (bytes):
#define PF_OFF   0u
#define AF_OFF   8388608u
#define INV_OFF  16777216u
#define PCK_OFF  16793600u
#define DONE_OFF 16826368u
#define WS_NEED  16826432u

// Prep: grid 128, one block per 32-row frag-block b. Writes Pf/Af in
// fragment order with perfectly coalesced 16B stores: global ushort idx
// within b's region = (i*256 + t)*8; decode g=(i*256+t): kh16=g>>6,
// lh=(g>>5)&1, l31=g&31 -> row=b*32+l31, k=[kh16*16+lh*8, +8).
// Source reads: lanes j and j+32 cover adjacent 32B halves of a 64B line.
// Also: anchor norms (8 partials/row via LDS), zero packed rows, zero done.
__global__ __launch_bounds__(256) void prep_kernel(const float* __restrict__ x,
                                                   unsigned short* __restrict__ Pf,
                                                   unsigned short* __restrict__ Af,
                                                   float* __restrict__ inv_an,
                                                   u64* __restrict__ packed,
                                                   unsigned int* __restrict__ done) {
    __shared__ float rsum[256];
    const int b = blockIdx.x;
    const int t = threadIdx.x;
    const int l31 = t & 31;
    const int lh = (t >> 5) & 1;
    const int row = b * 32 + l31;

    const float* px = x + (size_t)row * XSTR;
    unsigned short* pdst = Pf + (size_t)b * 32768;
    unsigned short* adst = Af + (size_t)b * 32768;

    float s = 0.0f;
#pragma unroll
    for (int i = 0; i < 16; ++i) {
        const int g = i * 256 + t;
        const int kcol = (g >> 6) * 16 + lh * 8;

        float4 p0 = *(const float4*)(px + kcol);
        float4 p1 = *(const float4*)(px + kcol + 4);
        float4 a0 = *(const float4*)(px + DDIM + kcol);
        float4 a1 = *(const float4*)(px + DDIM + kcol + 4);

        ushort4 h0 = make_ushort4(f2bf(p0.x), f2bf(p0.y), f2bf(p0.z), f2bf(p0.w));
        ushort4 h1 = make_ushort4(f2bf(p1.x), f2bf(p1.y), f2bf(p1.z), f2bf(p1.w));
        *(ushort4*)(pdst + g * 8) = h0;
        *(ushort4*)(pdst + g * 8 + 4) = h1;

        ushort4 g0 = make_ushort4(f2bf(a0.x), f2bf(a0.y), f2bf(a0.z), f2bf(a0.w));
        ushort4 g1 = make_ushort4(f2bf(a1.x), f2bf(a1.y), f2bf(a1.z), f2bf(a1.w));
        *(ushort4*)(adst + g * 8) = g0;
        *(ushort4*)(adst + g * 8 + 4) = g1;

        s += a0.x * a0.x + a0.y * a0.y + a0.z * a0.z + a0.w * a0.w;
        s += a1.x * a1.x + a1.y * a1.y + a1.z * a1.z + a1.w * a1.w;
    }
    rsum[t] = s;
    __syncthreads();
    if (t < 32) {
        float tot = 0.0f;
#pragma unroll
        for (int w = 0; w < 8; ++w) tot += rsum[t + 32 * w];
        inv_an[b * 32 + t] = 1.0f / sqrtf(tot);
        packed[b * 32 + t] = 0ULL;
        if (b == 0 && t == 0) *done = 0u;
    }
}

// Fragment load: frag-block blk, 16-k step kh -> byte blk*65536 + kh*1024 + lane*16.
#define FRAG(base, blk, kh) (*(const bf16x8*)((base) + (((size_t)(blk)) << 16) + ((kh) << 10)))

// MFMA GEMM + argmax + fused finalize. LDS-free, barrier-free K-loop.
// 256x256 block tile, 4 waves (2x2) of 128x128. Grid 256, XCD-swizzled
// (bid&7 = XCD, 4(r) x 8(c) region of the 16x16 tile grid).
__global__ __launch_bounds__(256, 1) void mfma_gemm_argmax(const unsigned short* __restrict__ Pf,
                                                           const unsigned short* __restrict__ Af,
                                                           const float* __restrict__ inv_an,
                                                           u64* __restrict__ packed,
                                                           unsigned int* __restrict__ done,
                                                           float* __restrict__ out) {
    __shared__ unsigned int lastflag;
    __shared__ int cnt[4];

    const int bid = blockIdx.x;
    const int xcd = bid & 7;
    const int slt = bid >> 3;                       // 0..31
    const int rblk = (xcd >> 1) * 4 + (slt >> 3);   // 0..15
    const int cblk = (xcd & 1) * 8 + (slt & 7);     // 0..15
    const int r0 = rblk * 256;
    const int c0 = cblk * 256;

    const int wave = threadIdx.x >> 6;
    const int lane = threadIdx.x & 63;
    const int l31 = lane & 31;
    const int lh = lane >> 5;
    const int wm = wave & 1;   // m-half: rows wm*128..+127
    const int wn = wave >> 1;  // n-half: cols wn*128..+127

    const int mb0 = rblk * 8 + wm * 4;  // first 32-row frag-block
    const int nb0 = cblk * 8 + wn * 4;  // first 32-col frag-block

    const char* pP = (const char*)Pf + (size_t)lane * 16 + ((size_t)mb0 << 16);
    const char* pA = (const char*)Af + (size_t)lane * 16 + ((size_t)nb0 << 16);

    f32x16 zero16 = {0.f,0.f,0.f,0.f,0.f,0.f,0.f,0.f,0.f,0.f,0.f,0.f,0.f,0.f,0.f,0.f};
    f32x16 acc[4][4];
#pragma unroll
    for (int i = 0; i < 4; ++i)
#pragma unroll
        for (int j = 0; j < 4; ++j) acc[i][j] = zero16;

    bf16x8 phA[4], aaA[4], phB[4], aaB[4];

    // preload kh=0 into A regs
#pragma unroll
    for (int q = 0; q < 4; ++q) { phA[q] = FRAG(pP, q, 0); aaA[q] = FRAG(pA, q, 0); }

    for (int kh = 0; kh < 64; kh += 2) {
        // load kh+1 into B regs
#pragma unroll
        for (int q = 0; q < 4; ++q) { phB[q] = FRAG(pP, q, kh + 1); aaB[q] = FRAG(pA, q, kh + 1); }

        // compute kh with A regs
#pragma unroll
        for (int mt = 0; mt < 4; ++mt)
#pragma unroll
            for (int nt = 0; nt < 4; ++nt)
                acc[mt][nt] = __builtin_amdgcn_mfma_f32_32x32x16_bf16(phA[mt], aaA[nt], acc[mt][nt], 0, 0, 0);

        // load kh+2 into A regs
        if (kh + 2 < 64) {
#pragma unroll
            for (int q = 0; q < 4; ++q) { phA[q] = FRAG(pP, q, kh + 2); aaA[q] = FRAG(pA, q, kh + 2); }
        }

        // compute kh+1 with B regs
#pragma unroll
        for (int mt = 0; mt < 4; ++mt)
#pragma unroll
            for (int nt = 0; nt < 4; ++nt)
                acc[mt][nt] = __builtin_amdgcn_mfma_f32_32x32x16_bf16(phB[mt], aaB[nt], acc[mt][nt], 0, 0, 0);
    }

    // ---- epilogue ----
    float ian[4];
#pragma unroll
    for (int nt = 0; nt < 4; ++nt) ian[nt] = inv_an[c0 + wn * 128 + nt * 32 + l31];

    // 32x32 C/D layout (m74/m101): col = lane&31, row = (reg&3)+8*(reg>>2)+4*(lane>>5)
#pragma unroll
    for (int mt = 0; mt < 4; ++mt)
#pragma unroll
        for (int reg = 0; reg < 16; ++reg) {
            const int row = r0 + wm * 128 + mt * 32 + (reg & 3) + 8 * (reg >> 2) + 4 * lh;
            u64 best = 0ULL;
#pragma unroll
            for (int nt = 0; nt < 4; ++nt) {
                const int col = c0 + wn * 128 + nt * 32 + l31;
                const float v = acc[mt][nt][reg] * ian[nt];
                const u64 p = ((u64)fkey(v) << 32) | (unsigned int)(~col);
                best = best > p ? best : p;
            }
#pragma unroll
            for (int m = 1; m <= 16; m <<= 1) {
                const u64 o = shfl_xor_u64(best, m);
                best = best > o ? best : o;
            }
            if (l31 == 0) atomicMax(&packed[row], best);
        }

    // ---- fused finalize: last block counts and writes out ----
    __syncthreads();
    if (threadIdx.x == 0) {
        __threadfence();  // publish this block's atomicMax results
        unsigned int old = atomicAdd(done, 1u);
        lastflag = (old == 255u) ? 1u : 0u;
    }
    __syncthreads();
    if (lastflag) {
        int c = 0;
        for (int r = threadIdx.x; r < NROWS; r += 256) {
            u64 v = atomicAdd(&packed[r], 0ULL);  // device-coherent read
            unsigned int col = ~(unsigned int)(v & 0xFFFFFFFFULL);
            c += (col == (unsigned int)r) ? 1 : 0;
        }
#pragma unroll
        for (int off = 32; off > 0; off >>= 1) c += __shfl_down(c, off, 64);
        if ((threadIdx.x & 63) == 0) cnt[threadIdx.x >> 6] = c;
        __syncthreads();
        if (threadIdx.x == 0) {
            out[0] = 1.0f;  // exp(temploss - stop_gradient(temploss)) == 1 exactly
            out[1] = 100.0f * (float)(cnt[0] + cnt[1] + cnt[2] + cnt[3]) / (float)NROWS;
        }
    }
}

// ---------------- fallback fp32 path (proven R1) ----------------
__global__ __launch_bounds__(256) void norms_kernel(const float* __restrict__ x,
                                                    float* __restrict__ inv_an,
                                                    u64* __restrict__ packed) {
    int gid  = blockIdx.x * 256 + threadIdx.x;
    int j    = gid >> 6;
    int lane = threadIdx.x & 63;
    if (gid < NROWS) packed[gid] = 0ULL;
    const float4* a = (const float4*)(x + (size_t)j * XSTR + DDIM);
    float s = 0.0f;
#pragma unroll
    for (int i = 0; i < 4; ++i) {
        float4 v = a[lane + i * 64];
        s += v.x * v.x + v.y * v.y + v.z * v.z + v.w * v.w;
    }
#pragma unroll
    for (int off = 32; off > 0; off >>= 1) s += __shfl_down(s, off, 64);
    if (lane == 0) inv_an[j] = 1.0f / sqrtf(s);
}

__global__ __launch_bounds__(256) void gemm_argmax_kernel(const float* __restrict__ x,
                                                          const float* __restrict__ inv_an,
                                                          u64* __restrict__ packed) {
    __shared__ __align__(16) float Pt[16][128];
    __shared__ __align__(16) float At[16][128];
    const int r0 = blockIdx.x * 128;
    const int c0 = blockIdx.y * 128;
    const int t = threadIdx.x;
    const int tx = t & 15;
    const int ty = t >> 4;
    const int srow = t >> 1;
    const int skq = (t & 1) * 8;
    float acc[8][8];
#pragma unroll
    for (int r = 0; r < 8; ++r)
#pragma unroll
        for (int c = 0; c < 8; ++c) acc[r][c] = 0.0f;
    const float* gp = x + (size_t)(r0 + srow) * XSTR + skq;
    const float* ga = x + (size_t)(c0 + srow) * XSTR + DDIM + skq;
    for (int k0 = 0; k0 < DDIM; k0 += 16) {
        __syncthreads();
        float4 p0 = *(const float4*)(gp + k0);
        float4 p1 = *(const float4*)(gp + k0 + 4);
        float4 a0 = *(const float4*)(ga + k0);
        float4 a1 = *(const float4*)(ga + k0 + 4);
        Pt[skq + 0][srow] = p0.x; Pt[skq + 1][srow] = p0.y;
        Pt[skq + 2][srow] = p0.z; Pt[skq + 3][srow] = p0.w;
        Pt[skq + 4][srow] = p1.x; Pt[skq + 5][srow] = p1.y;
        Pt[skq + 6][srow] = p1.z; Pt[skq + 7][srow] = p1.w;
        At[skq + 0][srow] = a0.x; At[skq + 1][srow] = a0.y;
        At[skq + 2][srow] = a0.z; At[skq + 3][srow] = a0.w;
        At[skq + 4][srow] = a1.x; At[skq + 5][srow] = a1.y;
        At[skq + 6][srow] = a1.z; At[skq + 7][srow] = a1.w;
        __syncthreads();
#pragma unroll
        for (int kk = 0; kk < 16; ++kk) {
            float pr[8], ar[8];
            *(float4*)&pr[0] = *(const float4*)&Pt[kk][ty * 8];
            *(float4*)&pr[4] = *(const float4*)&Pt[kk][ty * 8 + 4];
            *(float4*)&ar[0] = *(const float4*)&At[kk][tx * 8];
            *(float4*)&ar[4] = *(const float4*)&At[kk][tx * 8 + 4];
#pragma unroll
            for (int r = 0; r < 8; ++r)
#pragma unroll
                for (int c = 0; c < 8; ++c) acc[r][c] += pr[r] * ar[c];
        }
    }
    float ian[8];
#pragma unroll
    for (int c = 0; c < 8; ++c) ian[c] = inv_an[c0 + tx * 8 + c];
#pragma unroll
    for (int r = 0; r < 8; ++r) {
        int row = r0 + ty * 8 + r;
        u64 best = 0ULL;
#pragma unroll
        for (int c = 0; c < 8; ++c) {
            int col = c0 + tx * 8 + c;
            float v = acc[r][c] * ian[c];
            u64 p = ((u64)fkey(v) << 32) | (unsigned int)(~col);
            best = best > p ? best : p;
        }
#pragma unroll
        for (int m = 1; m <= 8; m <<= 1) {
            u64 o = shfl_xor_u64(best, m);
            best = best > o ? best : o;
        }
        if (tx == 0) atomicMax(&packed[row], best);
    }
}

__global__ __launch_bounds__(256) void finalize_kernel(const u64* __restrict__ packed,
                                                       float* __restrict__ out) {
    __shared__ int cnt_s;
    int t = threadIdx.x;
    if (t == 0) cnt_s = 0;
    __syncthreads();
    int c = 0;
    for (int r = t; r < NROWS; r += 256) {
        unsigned int col = ~(unsigned int)(packed[r] & 0xFFFFFFFFULL);
        c += (col == (unsigned int)r) ? 1 : 0;
    }
#pragma unroll
    for (int off = 32; off > 0; off >>= 1) c += __shfl_down(c, off, 64);
    if ((t & 63) == 0) atomicAdd(&cnt_s, c);
    __syncthreads();
    if (t == 0) {
        out[0] = 1.0f;
        out[1] = 100.0f * (float)cnt_s / (float)NROWS;
    }
}

extern "C" void kernel_launch(void* const* d_in, const int* in_sizes, int n_in,
                              void* d_out, int out_size, void* d_ws, size_t ws_size,
                              hipStream_t stream) {
    (void)in_sizes; (void)n_in; (void)out_size;
    const float* x = (const float*)d_in[0];
    float* out = (float*)d_out;

    if (ws_size >= (size_t)WS_NEED) {
        char* ws = (char*)d_ws;
        unsigned short* Pf = (unsigned short*)(ws + PF_OFF);
        unsigned short* Af = (unsigned short*)(ws + AF_OFF);
        float* inv_an = (float*)(ws + INV_OFF);
        u64* packed = (u64*)(ws + PCK_OFF);
        unsigned int* done = (unsigned int*)(ws + DONE_OFF);

        prep_kernel<<<128, 256, 0, stream>>>(x, Pf, Af, inv_an, packed, done);
        mfma_gemm_argmax<<<256, 256, 0, stream>>>(Pf, Af, inv_an, packed, done, out);
    } else {
        float* inv_an = (float*)d_ws;
        u64* packed = (u64*)((char*)d_ws + NROWS * sizeof(float));
        norms_kernel<<<NROWS / 4, 256, 0, stream>>>(x, inv_an, packed);
        dim3 grid(NROWS / 128, NROWS / 128);
        gemm_argmax_kernel<<<grid, 256, 0, stream>>>(x, inv_an, packed);
        finalize_kernel<<<1, 256, 0, stream>>>(packed, out);
    }
}

// Round 12
// 131.074 us; speedup vs baseline: 1.4198x; 1.0058x over previous
//
#include <hip/hip_runtime.h>

// x (4096, 2, 1024) fp32.  P_i = x[i,0,:], A_j = x[i,1,:]
// out[0] = 1.0 exactly; out[1] = prec1 = 100*mean(argmax_j sim[i,j] == i)
// argmax_j sim[i,j] == argmax_j dot(P_i,A_j)*inv_norm(A_j).
// R12: R11's register-direct 1-pass bf16 GEMM reshaped for latency hiding:
// 512-thread blocks, 8 waves of 64x128 (acc=128 AGPR -> 2 waves/SIMD TLP),
// 3-set rotating frag pipeline (prefetch depth 2 ~= 1032 cyc per load).
// Frag-order workspace (R4/R9/R11-verified map): block b region = 64KB at
// b*65536; byte = kh*1024 + lane*16 -> (row=l31, k=kh*16+lh*8..+8).

#define NROWS 4096
#define DDIM  1024
#define XSTR  2048

typedef unsigned int u32;
typedef unsigned long long u64;
typedef __attribute__((ext_vector_type(8))) short bf16x8;
typedef __attribute__((ext_vector_type(16))) float f32x16;

__device__ __forceinline__ unsigned int fkey(float f) {
    unsigned int u = __float_as_uint(f);
    return (u & 0x80000000u) ? ~u : (u | 0x80000000u);
}

__device__ __forceinline__ u64 shfl_xor_u64(u64 v, int m) {
    unsigned int lo = (unsigned int)v;
    unsigned int hi = (unsigned int)(v >> 32);
    lo = __shfl_xor(lo, m, 64);
    hi = __shfl_xor(hi, m, 64);
    return ((u64)hi << 32) | lo;
}

__device__ __forceinline__ unsigned short f2bf(float f) {
    unsigned u = __float_as_uint(f);
    return (unsigned short)((u + 0x7FFFu + ((u >> 16) & 1u)) >> 16);
}

// Workspace layout (bytes):
#define PF_OFF   0u
#define AF_OFF   8388608u
#define INV_OFF  16777216u
#define PCK_OFF  16793600u
#define DONE_OFF 16826368u
#define WS_NEED  16826432u

// Prep (R11-proven): grid 128, one block per 32-row frag-block b. Coalesced
// 16B stores in fragment order; anchor norms; zero packed rows and done.
__global__ __launch_bounds__(256) void prep_kernel(const float* __restrict__ x,
                                                   unsigned short* __restrict__ Pf,
                                                   unsigned short* __restrict__ Af,
                                                   float* __restrict__ inv_an,
                                                   u64* __restrict__ packed,
                                                   unsigned int* __restrict__ done) {
    __shared__ float rsum[256];
    const int b = blockIdx.x;
    const int t = threadIdx.x;
    const int l31 = t & 31;
    const int lh = (t >> 5) & 1;
    const int row = b * 32 + l31;

    const float* px = x + (size_t)row * XSTR;
    unsigned short* pdst = Pf + (size_t)b * 32768;
    unsigned short* adst = Af + (size_t)b * 32768;

    float s = 0.0f;
#pragma unroll
    for (int i = 0; i < 16; ++i) {
        const int g = i * 256 + t;
        const int kcol = (g >> 6) * 16 + lh * 8;

        float4 p0 = *(const float4*)(px + kcol);
        float4 p1 = *(const float4*)(px + kcol + 4);
        float4 a0 = *(const float4*)(px + DDIM + kcol);
        float4 a1 = *(const float4*)(px + DDIM + kcol + 4);

        *(ushort4*)(pdst + g * 8) = make_ushort4(f2bf(p0.x), f2bf(p0.y), f2bf(p0.z), f2bf(p0.w));
        *(ushort4*)(pdst + g * 8 + 4) = make_ushort4(f2bf(p1.x), f2bf(p1.y), f2bf(p1.z), f2bf(p1.w));
        *(ushort4*)(adst + g * 8) = make_ushort4(f2bf(a0.x), f2bf(a0.y), f2bf(a0.z), f2bf(a0.w));
        *(ushort4*)(adst + g * 8 + 4) = make_ushort4(f2bf(a1.x), f2bf(a1.y), f2bf(a1.z), f2bf(a1.w));

        s += a0.x * a0.x + a0.y * a0.y + a0.z * a0.z + a0.w * a0.w;
        s += a1.x * a1.x + a1.y * a1.y + a1.z * a1.z + a1.w * a1.w;
    }
    rsum[t] = s;
    __syncthreads();
    if (t < 32) {
        float tot = 0.0f;
#pragma unroll
        for (int w = 0; w < 8; ++w) tot += rsum[t + 32 * w];
        inv_an[b * 32 + t] = 1.0f / sqrtf(tot);
        packed[b * 32 + t] = 0ULL;
        if (b == 0 && t == 0) *done = 0u;
    }
}

// Fragment load: frag-block blk, 16-k step kh -> byte blk*65536 + kh*1024 + lane*16.
#define FRAG(base, blk, kh) (*(const bf16x8*)((base) + (((size_t)(blk)) << 16) + ((kh) << 10)))

// MFMA GEMM + argmax + fused finalize. LDS-free, barrier-free K-loop.
// 256x256 block tile, 8 waves (4m x 2n) of 64x128. Grid 256, XCD-swizzled.
// 3-set rotating frag pipeline: compute set kh%3 while set (kh+2)%3 loads.
__global__ __launch_bounds__(512, 2) void mfma_gemm_argmax(const unsigned short* __restrict__ Pf,
                                                           const unsigned short* __restrict__ Af,
                                                           const float* __restrict__ inv_an,
                                                           u64* __restrict__ packed,
                                                           unsigned int* __restrict__ done,
                                                           float* __restrict__ out) {
    __shared__ unsigned int lastflag;
    __shared__ int cnt[8];

    const int bid = blockIdx.x;
    const int xcd = bid & 7;
    const int slt = bid >> 3;                       // 0..31
    const int rblk = (xcd >> 1) * 4 + (slt >> 3);   // 0..15
    const int cblk = (xcd & 1) * 8 + (slt & 7);     // 0..15
    const int r0 = rblk * 256;
    const int c0 = cblk * 256;

    const int wave = threadIdx.x >> 6;  // 0..7
    const int lane = threadIdx.x & 63;
    const int l31 = lane & 31;
    const int lh = lane >> 5;
    const int wm = wave & 3;   // m-quarter: rows wm*64..+63
    const int wn = wave >> 2;  // n-half:    cols wn*128..+127

    const int mb0 = rblk * 8 + wm * 2;  // first 32-row frag-block (2 total)
    const int nb0 = cblk * 8 + wn * 4;  // first 32-col frag-block (4 total)

    const char* pP = (const char*)Pf + (size_t)lane * 16 + ((size_t)mb0 << 16);
    const char* pA = (const char*)Af + (size_t)lane * 16 + ((size_t)nb0 << 16);

    f32x16 zero16 = {0.f,0.f,0.f,0.f,0.f,0.f,0.f,0.f,0.f,0.f,0.f,0.f,0.f,0.f,0.f,0.f};
    f32x16 acc[2][4];
#pragma unroll
    for (int i = 0; i < 2; ++i)
#pragma unroll
        for (int j = 0; j < 4; ++j) acc[i][j] = zero16;

    // 3-set rotating register pipeline
    bf16x8 ph[3][2], aa[3][4];
#pragma unroll
    for (int q = 0; q < 2; ++q) { ph[0][q] = FRAG(pP, q, 0); ph[1][q] = FRAG(pP, q, 1); }
#pragma unroll
    for (int q = 0; q < 4; ++q) { aa[0][q] = FRAG(pA, q, 0); aa[1][q] = FRAG(pA, q, 1); }

#pragma unroll
    for (int kh = 0; kh < 64; ++kh) {
        const int cs = kh % 3;
        if (kh + 2 < 64) {
            const int ns = (kh + 2) % 3;
#pragma unroll
            for (int q = 0; q < 2; ++q) ph[ns][q] = FRAG(pP, q, kh + 2);
#pragma unroll
            for (int q = 0; q < 4; ++q) aa[ns][q] = FRAG(pA, q, kh + 2);
        }
#pragma unroll
        for (int mt = 0; mt < 2; ++mt)
#pragma unroll
            for (int nt = 0; nt < 4; ++nt)
                acc[mt][nt] = __builtin_amdgcn_mfma_f32_32x32x16_bf16(ph[cs][mt], aa[cs][nt], acc[mt][nt], 0, 0, 0);
    }

    // ---- epilogue ----
    float ian[4];
#pragma unroll
    for (int nt = 0; nt < 4; ++nt) ian[nt] = inv_an[c0 + wn * 128 + nt * 32 + l31];

    // 32x32 C/D layout (m74/m101): col = lane&31, row = (reg&3)+8*(reg>>2)+4*(lane>>5)
#pragma unroll
    for (int mt = 0; mt < 2; ++mt)
#pragma unroll
        for (int reg = 0; reg < 16; ++reg) {
            const int row = r0 + wm * 64 + mt * 32 + (reg & 3) + 8 * (reg >> 2) + 4 * lh;
            u64 best = 0ULL;
#pragma unroll
            for (int nt = 0; nt < 4; ++nt) {
                const int col = c0 + wn * 128 + nt * 32 + l31;
                const float v = acc[mt][nt][reg] * ian[nt];
                const u64 p = ((u64)fkey(v) << 32) | (unsigned int)(~col);
                best = best > p ? best : p;
            }
#pragma unroll
            for (int m = 1; m <= 16; m <<= 1) {
                const u64 o = shfl_xor_u64(best, m);
                best = best > o ? best : o;
            }
            if (l31 == 0) atomicMax(&packed[row], best);
        }

    // ---- fused finalize: last block counts and writes out ----
    __syncthreads();
    if (threadIdx.x == 0) {
        __threadfence();  // publish this block's atomicMax results
        unsigned int old = atomicAdd(done, 1u);
        lastflag = (old == 255u) ? 1u : 0u;
    }
    __syncthreads();
    if (lastflag) {
        int c = 0;
        for (int r = threadIdx.x; r < NROWS; r += 512) {
            u64 v = atomicAdd(&packed[r], 0ULL);  // device-coherent read
            unsigned int col = ~(unsigned int)(v & 0xFFFFFFFFULL);
            c += (col == (unsigned int)r) ? 1 : 0;
        }
#pragma unroll
        for (int off = 32; off > 0; off >>= 1) c += __shfl_down(c, off, 64);
        if ((threadIdx.x & 63) == 0) cnt[threadIdx.x >> 6] = c;
        __syncthreads();
        if (threadIdx.x == 0) {
            int tot = 0;
#pragma unroll
            for (int w = 0; w < 8; ++w) tot += cnt[w];
            out[0] = 1.0f;  // exp(temploss - stop_gradient(temploss)) == 1 exactly
            out[1] = 100.0f * (float)tot / (float)NROWS;
        }
    }
}

// ---------------- fallback fp32 path (proven R1) ----------------
__global__ __launch_bounds__(256) void norms_kernel(const float* __restrict__ x,
                                                    float* __restrict__ inv_an,
                                                    u64* __restrict__ packed) {
    int gid  = blockIdx.x * 256 + threadIdx.x;
    int j    = gid >> 6;
    int lane = threadIdx.x & 63;
    if (gid < NROWS) packed[gid] = 0ULL;
    const float4* a = (const float4*)(x + (size_t)j * XSTR + DDIM);
    float s = 0.0f;
#pragma unroll
    for (int i = 0; i < 4; ++i) {
        float4 v = a[lane + i * 64];
        s += v.x * v.x + v.y * v.y + v.z * v.z + v.w * v.w;
    }
#pragma unroll
    for (int off = 32; off > 0; off >>= 1) s += __shfl_down(s, off, 64);
    if (lane == 0) inv_an[j] = 1.0f / sqrtf(s);
}

__global__ __launch_bounds__(256) void gemm_argmax_kernel(const float* __restrict__ x,
                                                          const float* __restrict__ inv_an,
                                                          u64* __restrict__ packed) {
    __shared__ __align__(16) float Pt[16][128];
    __shared__ __align__(16) float At[16][128];
    const int r0 = blockIdx.x * 128;
    const int c0 = blockIdx.y * 128;
    const int t = threadIdx.x;
    const int tx = t & 15;
    const int ty = t >> 4;
    const int srow = t >> 1;
    const int skq = (t & 1) * 8;
    float acc[8][8];
#pragma unroll
    for (int r = 0; r < 8; ++r)
#pragma unroll
        for (int c = 0; c < 8; ++c) acc[r][c] = 0.0f;
    const float* gp = x + (size_t)(r0 + srow) * XSTR + skq;
    const float* ga = x + (size_t)(c0 + srow) * XSTR + DDIM + skq;
    for (int k0 = 0; k0 < DDIM; k0 += 16) {
        __syncthreads();
        float4 p0 = *(const float4*)(gp + k0);
        float4 p1 = *(const float4*)(gp + k0 + 4);
        float4 a0 = *(const float4*)(ga + k0);
        float4 a1 = *(const float4*)(ga + k0 + 4);
        Pt[skq + 0][srow] = p0.x; Pt[skq + 1][srow] = p0.y;
        Pt[skq + 2][srow] = p0.z; Pt[skq + 3][srow] = p0.w;
        Pt[skq + 4][srow] = p1.x; Pt[skq + 5][srow] = p1.y;
        Pt[skq + 6][srow] = p1.z; Pt[skq + 7][srow] = p1.w;
        At[skq + 0][srow] = a0.x; At[skq + 1][srow] = a0.y;
        At[skq + 2][srow] = a0.z; At[skq + 3][srow] = a0.w;
        At[skq + 4][srow] = a1.x; At[skq + 5][srow] = a1.y;
        At[skq + 6][srow] = a1.z; At[skq + 7][srow] = a1.w;
        __syncthreads();
#pragma unroll
        for (int kk = 0; kk < 16; ++kk) {
            float pr[8], ar[8];
            *(float4*)&pr[0] = *(const float4*)&Pt[kk][ty * 8];
            *(float4*)&pr[4] = *(const float4*)&Pt[kk][ty * 8 + 4];
            *(float4*)&ar[0] = *(const float4*)&At[kk][tx * 8];
            *(float4*)&ar[4] = *(const float4*)&At[kk][tx * 8 + 4];
#pragma unroll
            for (int r = 0; r < 8; ++r)
#pragma unroll
                for (int c = 0; c < 8; ++c) acc[r][c] += pr[r] * ar[c];
        }
    }
    float ian[8];
#pragma unroll
    for (int c = 0; c < 8; ++c) ian[c] = inv_an[c0 + tx * 8 + c];
#pragma unroll
    for (int r = 0; r < 8; ++r) {
        int row = r0 + ty * 8 + r;
        u64 best = 0ULL;
#pragma unroll
        for (int c = 0; c < 8; ++c) {
            int col = c0 + tx * 8 + c;
            float v = acc[r][c] * ian[c];
            u64 p = ((u64)fkey(v) << 32) | (unsigned int)(~col);
            best = best > p ? best : p;
        }
#pragma unroll
        for (int m = 1; m <= 8; m <<= 1) {
            u64 o = shfl_xor_u64(best, m);
            best = best > o ? best : o;
        }
        if (tx == 0) atomicMax(&packed[row], best);
    }
}

__global__ __launch_bounds__(256) void finalize_kernel(const u64* __restrict__ packed,
                                                       float* __restrict__ out) {
    __shared__ int cnt_s;
    int t = threadIdx.x;
    if (t == 0) cnt_s = 0;
    __syncthreads();
    int c = 0;
    for (int r = t; r < NROWS; r += 256) {
        unsigned int col = ~(unsigned int)(packed[r] & 0xFFFFFFFFULL);
        c += (col == (unsigned int)r) ? 1 : 0;
    }
#pragma unroll
    for (int off = 32; off > 0; off >>= 1) c += __shfl_down(c, off, 64);
    if ((t & 63) == 0) atomicAdd(&cnt_s, c);
    __syncthreads();
    if (t == 0) {
        out[0] = 1.0f;
        out[1] = 100.0f * (float)cnt_s / (float)NROWS;
    }
}

extern "C" void kernel_launch(void* const* d_in, const int* in_sizes, int n_in,
                              void* d_out, int out_size, void* d_ws, size_t ws_size,
                              hipStream_t stream) {
    (void)in_sizes; (void)n_in; (void)out_size;
    const float* x = (const float*)d_in[0];
    float* out = (float*)d_out;

    if (ws_size >= (size_t)WS_NEED) {
        char* ws = (char*)d_ws;
        unsigned short* Pf = (unsigned short*)(ws + PF_OFF);
        unsigned short* Af = (unsigned short*)(ws + AF_OFF);
        float* inv_an = (float*)(ws + INV_OFF);
        u64* packed = (u64*)(ws + PCK_OFF);
        unsigned int* done = (unsigned int*)(ws + DONE_OFF);

        prep_kernel<<<128, 256, 0, stream>>>(x, Pf, Af, inv_an, packed, done);
        mfma_gemm_argmax<<<256, 512, 0, stream>>>(Pf, Af, inv_an, packed, done, out);
    } else {
        float* inv_an = (float*)d_ws;
        u64* packed = (u64*)((char*)d_ws + NROWS * sizeof(float));
        norms_kernel<<<NROWS / 4, 256, 0, stream>>>(x, inv_an, packed);
        dim3 grid(NROWS / 128, NROWS / 128);
        gemm_argmax_kernel<<<grid, 256, 0, stream>>>(x, inv_an, packed);
        finalize_kernel<<<1, 256, 0, stream>>>(packed, out);
    }
}